// Round 2
// baseline (1242.918 us; speedup 1.0000x reference)
//
#include <hip/hip_runtime.h>
#include <math.h>

#define CCH   50
#define HH    256
#define WW    256
#define BATCH 16
#define HSZ   64
#define WSZ   64
#define NTOP  240

// ---------------- Kernel 1: conv3x3 (50->50) + ReLU ----------------
// 2 vertical pixels per thread, co chunked 2x25 so accumulators provably fit
// in registers. Weights are wave-uniform -> scalar loads (SGPR operand FMAs).
__global__ __launch_bounds__(256, 4) void conv1_relu_k(
    const float* __restrict__ in, const float* __restrict__ w1,
    const float* __restrict__ b1, float* __restrict__ x1) {
  int blk = blockIdx.x;
  int b = blk >> 7;                 // 128 blocks per batch image
  int hh = blk & 127;
  int h0 = hh * 2;                  // this thread does rows h0, h0+1
  int w = threadIdx.x;
  const float* ip = in + ((size_t)b * CCH << 16) + h0 * WW + w;
  float* op = x1 + ((size_t)b * CCH << 16) + h0 * WW + w;

  bool hm = h0 > 0;                 // row h0-1 valid
  bool hp = hh < 127;               // row h0+2 valid
  bool wm = w > 0, wp = w < WW - 1;

  for (int cc = 0; cc < 2; ++cc) {
    const float* wb = w1 + cc * 25 * (CCH * 9);
    const float* bb = b1 + cc * 25;
    float acc0[25], acc1[25];
#pragma unroll
    for (int co = 0; co < 25; ++co) { acc0[co] = bb[co]; acc1[co] = bb[co]; }

    for (int ci = 0; ci < CCH; ++ci) {
      const float* p = ip + ((size_t)ci << 16);
      // 4 rows x 3 cols shared between the two output pixels
      float a0 = (hm && wm) ? p[-257] : 0.f;
      float a1 = hm         ? p[-256] : 0.f;
      float a2 = (hm && wp) ? p[-255] : 0.f;
      float r0 = wm         ? p[-1]   : 0.f;
      float r1 =              p[0];
      float r2 = wp         ? p[1]    : 0.f;
      float c0 = wm         ? p[255]  : 0.f;
      float c1 =              p[256];
      float c2 = wp         ? p[257]  : 0.f;
      float d0 = (hp && wm) ? p[511]  : 0.f;
      float d1 = hp         ? p[512]  : 0.f;
      float d2 = (hp && wp) ? p[513]  : 0.f;
      const float* wr = wb + ci * 9;
#pragma unroll
      for (int co = 0; co < 25; ++co) {
        const float* k9 = wr + co * (CCH * 9);
        float k0 = k9[0], k1 = k9[1], k2 = k9[2], k3 = k9[3], k4 = k9[4],
              k5 = k9[5], k6 = k9[6], k7 = k9[7], k8 = k9[8];
        float s0 = acc0[co], s1 = acc1[co];
        s0 = fmaf(k0, a0, s0); s0 = fmaf(k1, a1, s0); s0 = fmaf(k2, a2, s0);
        s0 = fmaf(k3, r0, s0); s0 = fmaf(k4, r1, s0); s0 = fmaf(k5, r2, s0);
        s0 = fmaf(k6, c0, s0); s0 = fmaf(k7, c1, s0); s0 = fmaf(k8, c2, s0);
        s1 = fmaf(k0, r0, s1); s1 = fmaf(k1, r1, s1); s1 = fmaf(k2, r2, s1);
        s1 = fmaf(k3, c0, s1); s1 = fmaf(k4, c1, s1); s1 = fmaf(k5, c2, s1);
        s1 = fmaf(k6, d0, s1); s1 = fmaf(k7, d1, s1); s1 = fmaf(k8, d2, s1);
        acc0[co] = s0; acc1[co] = s1;
      }
    }
#pragma unroll
    for (int co = 0; co < 25; ++co) {
      size_t co_off = (size_t)(cc * 25 + co) << 16;
      op[co_off]      = fmaxf(acc0[co], 0.f);
      op[co_off + WW] = fmaxf(acc1[co], 0.f);
    }
  }
}

// ---------------- Kernel 2: conv3x3 (50->2) + softmax[:,1] ----------------
__global__ __launch_bounds__(256) void conv2_softmax_k(
    const float* __restrict__ x1, const float* __restrict__ w2,
    const float* __restrict__ b2, float* __restrict__ sm) {
  int idx = blockIdx.x * 256 + threadIdx.x;
  int b = idx >> 16, hw = idx & 65535;
  int h = hw >> 8, w = hw & 255;
  const float* ip = x1 + (size_t)b * CCH * 65536 + hw;

  float a0 = b2[0], a1 = b2[1];
  bool hm = h > 0, hp = h < HH - 1, wm = w > 0, wp = w < WW - 1;

  for (int ci = 0; ci < CCH; ++ci) {
    const float* p = ip + (size_t)ci * 65536;
    float v0 = (hm && wm) ? p[-257] : 0.f;
    float v1 = hm         ? p[-256] : 0.f;
    float v2 = (hm && wp) ? p[-255] : 0.f;
    float v3 = wm         ? p[-1]   : 0.f;
    float v4 =              p[0];
    float v5 = wp         ? p[1]    : 0.f;
    float v6 = (hp && wm) ? p[255]  : 0.f;
    float v7 = hp         ? p[256]  : 0.f;
    float v8 = (hp && wp) ? p[257]  : 0.f;
    const float* q0 = w2 + ci * 9;
    const float* q1 = w2 + CCH * 9 + ci * 9;
    a0 = fmaf(q0[0], v0, a0); a0 = fmaf(q0[1], v1, a0); a0 = fmaf(q0[2], v2, a0);
    a0 = fmaf(q0[3], v3, a0); a0 = fmaf(q0[4], v4, a0); a0 = fmaf(q0[5], v5, a0);
    a0 = fmaf(q0[6], v6, a0); a0 = fmaf(q0[7], v7, a0); a0 = fmaf(q0[8], v8, a0);
    a1 = fmaf(q1[0], v0, a1); a1 = fmaf(q1[1], v1, a1); a1 = fmaf(q1[2], v2, a1);
    a1 = fmaf(q1[3], v3, a1); a1 = fmaf(q1[4], v4, a1); a1 = fmaf(q1[5], v5, a1);
    a1 = fmaf(q1[6], v6, a1); a1 = fmaf(q1[7], v7, a1); a1 = fmaf(q1[8], v8, a1);
  }
  // softmax over {a0,a1}, channel 1 = sigmoid(a1 - a0)
  sm[(size_t)b * 65536 + hw] = 1.f / (1.f + expf(a0 - a1));
}

// ---------------- Kernel 3: 4x4 avg pool + LeakyReLU(0.1) ----------------
__global__ __launch_bounds__(256) void pool_leaky_k(
    const float* __restrict__ sm, float* __restrict__ pool) {
  int idx = blockIdx.x * 256 + threadIdx.x;      // b*4096 + hs*64 + ws
  int b = idx >> 12, hw = idx & 4095;
  int hs = hw >> 6, ws = hw & 63;
  const float* p = sm + (size_t)b * 65536 + hs * 4 * WW + ws * 4;
  float s = 0.f;
#pragma unroll
  for (int r = 0; r < 4; ++r)
#pragma unroll
    for (int c = 0; c < 4; ++c) s += p[r * WW + c];
  s *= (1.f / 16.f);
  pool[idx] = (s >= 0.f) ? s : 0.1f * s;
}

// ---------------- Kernel 4: 25-tap learned mixing -> final_mask ----------------
__global__ __launch_bounds__(256) void mix_mask_k(
    const float* __restrict__ pool, const float* __restrict__ wk,
    const float* __restrict__ bk, float* __restrict__ mask_out) {
  int idx = blockIdx.x * 256 + threadIdx.x;      // b*4096 + hs*64 + ws
  int b = idx >> 12, hw = idx & 4095;
  int hs = hw >> 6, ws = hw & 63;
  float c = pool[idx];
  float s = 0.f;
#pragma unroll
  for (int i = 0; i < 5; ++i) {
#pragma unroll
    for (int j = 0; j < 5; ++j) {
      int y = hs + i - 2, x = ws + j - 2;
      float win = (y >= 0 && y < HSZ && x >= 0 && x < WSZ)
                      ? pool[(size_t)b * 4096 + y * WSZ + x] : 0.f;
      int k = i * 5 + j;
      s += (wk[k] * c + bk[k]) * win;
    }
  }
  mask_out[idx] = s;
}

// ---------------- Kernel 5: per-batch top-240 + ascending index sort ----------------
__global__ __launch_bounds__(256) void topk_sort_k(
    const float* __restrict__ mask, float* __restrict__ ob, float* __restrict__ oh,
    float* __restrict__ ow, int* __restrict__ idx_ws) {
  __shared__ unsigned long long keys[4096];
  __shared__ int sidx[256];
  int b = blockIdx.x, t = threadIdx.x;

  for (int i = t; i < 4096; i += 256) {
    float v = mask[(size_t)b * 4096 + i];
    unsigned u = __float_as_uint(v);
    u = (u & 0x80000000u) ? ~u : (u | 0x80000000u);   // order-preserving map
    u = ~u;                                            // ascending sort -> value desc
    keys[i] = ((unsigned long long)u << 12) | (unsigned)i;  // tie: lower idx first
  }
  __syncthreads();

  // bitonic sort 4096, ascending
  for (int k = 2; k <= 4096; k <<= 1) {
    for (int j = k >> 1; j > 0; j >>= 1) {
      for (int m = t; m < 2048; m += 256) {
        int i = ((m & ~(j - 1)) << 1) | (m & (j - 1));
        int l = i | j;
        bool up = ((i & k) == 0);
        unsigned long long a = keys[i], c = keys[l];
        if ((a > c) == up) { keys[i] = c; keys[l] = a; }
      }
      __syncthreads();
    }
  }

  // first 240 entries are top-k (value desc). Extract indices, sort ascending.
  sidx[t] = (t < NTOP) ? (int)(keys[t] & 0xFFFu) : 0x7FFFFFFF;
  __syncthreads();
  for (int k = 2; k <= 256; k <<= 1) {
    for (int j = k >> 1; j > 0; j >>= 1) {
      if (t < 128) {
        int i = ((t & ~(j - 1)) << 1) | (t & (j - 1));
        int l = i | j;
        bool up = ((i & k) == 0);
        int a = sidx[i], c = sidx[l];
        if ((a > c) == up) { sidx[i] = c; sidx[l] = a; }
      }
      __syncthreads();
    }
  }

  if (t < NTOP) {
    int id = sidx[t];
    int o = b * NTOP + t;
    ob[o] = (float)b;
    oh[o] = (float)(id >> 6);
    ow[o] = (float)(id & 63);
    idx_ws[o] = id;
  }
}

// ---------------- Kernel 6: gather 6x6 patches (pad=1, stride=4) ----------------
__global__ __launch_bounds__(256) void gather_patch_k(
    const float* __restrict__ in, const int* __restrict__ idx_ws,
    float* __restrict__ patches) {
  int p = blockIdx.x;                 // 0 .. B*240-1
  int b = p / NTOP;
  int id = idx_ws[p];
  int h = id >> 6, w = id & 63;
  int y0 = h * 4 - 1, x0 = w * 4 - 1;
  const float* base = in + (size_t)b * CCH * 65536;
  float* op = patches + (size_t)p * (CCH * 36);
  for (int e = threadIdx.x; e < CCH * 36; e += 256) {
    int c = e / 36;
    int r = (e - c * 36) / 6;
    int col = e - c * 36 - r * 6;
    int y = y0 + r, x = x0 + col;
    float v = 0.f;
    if (y >= 0 && y < HH && x >= 0 && x < WW)
      v = base[(size_t)c * 65536 + y * WW + x];
    op[e] = v;
  }
}

extern "C" void kernel_launch(void* const* d_in, const int* in_sizes, int n_in,
                              void* d_out, int out_size, void* d_ws, size_t ws_size,
                              hipStream_t stream) {
  const float* out_lr = (const float*)d_in[0];
  const float* W1 = (const float*)d_in[1];
  const float* b1 = (const float*)d_in[2];
  const float* W2 = (const float*)d_in[3];
  const float* b2 = (const float*)d_in[4];
  const float* Wk = (const float*)d_in[5];
  const float* bk = (const float*)d_in[6];

  // workspace layout
  float* x1   = (float*)d_ws;                 // 16*50*256*256 = 52,428,800
  float* sm   = x1 + (size_t)52428800;        // 16*256*256    =  1,048,576
  float* pool = sm + (size_t)1048576;         // 16*64*64      =     65,536
  int*  idxb  = (int*)(pool + 65536);         // 16*240        =      3,840

  // output layout (float32, concatenated in reference return order)
  float* out    = (float*)d_out;
  float* o_patch = out;                        // 3840*50*36 = 6,912,000
  float* o_b    = out + (size_t)6912000;       // 3840
  float* o_h    = o_b + 3840;                  // 3840
  float* o_w    = o_h + 3840;                  // 3840
  float* o_mask = o_w + 3840;                  // 16*4096 = 65,536

  conv1_relu_k<<<BATCH * 128, 256, 0, stream>>>(out_lr, W1, b1, x1);
  conv2_softmax_k<<<4096, 256, 0, stream>>>(x1, W2, b2, sm);
  pool_leaky_k<<<256, 256, 0, stream>>>(sm, pool);
  mix_mask_k<<<256, 256, 0, stream>>>(pool, Wk, bk, o_mask);
  topk_sort_k<<<BATCH, 256, 0, stream>>>(o_mask, o_b, o_h, o_w, idxb);
  gather_patch_k<<<BATCH * NTOP, 256, 0, stream>>>(out_lr, idxb, o_patch);
}

// Round 3
// 813.851 us; speedup vs baseline: 1.5272x; 1.5272x over previous
//
#include <hip/hip_runtime.h>
#include <math.h>

#define CCH   50
#define HH    256
#define WW    256
#define BATCH 16
#define HSZ   64
#define WSZ   64
#define NTOP  240

#define REPEAT25(M) M(0) M(1) M(2) M(3) M(4) M(5) M(6) M(7) M(8) M(9) \
  M(10) M(11) M(12) M(13) M(14) M(15) M(16) M(17) M(18) M(19) \
  M(20) M(21) M(22) M(23) M(24)

// ---------------- Kernel 1: conv3x3 (50->50) + ReLU ----------------
// Weights for a 25-channel output chunk staged in LDS (60 KB), read as
// broadcast ds_read_b128 (uniform address -> no conflicts, 16B/read).
// 2 vertical pixels per thread, 50 NAMED accumulators (no arrays -> no
// scratch). Block = 512 threads = 4 rows x 256 cols.
__global__ __launch_bounds__(512, 4) void conv1_relu_k(
    const float* __restrict__ in, const float* __restrict__ w1,
    const float* __restrict__ b1, float* __restrict__ x1) {
  __shared__ float wlds[50 * 25 * 12];          // [ci][co][12] (9 used)

  int bx = blockIdx.x;
  int c  = bx & 1;                  // co-chunk: channels [c*25, c*25+25)
  int rg = (bx >> 1) & 63;          // row group (4 rows each)
  int b  = bx >> 7;                 // batch
  int cbase = c * 25;

  int t  = threadIdx.x;
  int w  = t & 255;
  int rp = t >> 8;                  // 0 or 1: which row-pair
  int h0 = rg * 4 + rp * 2;

  // ---- stage weight chunk into LDS ----
  for (int e = t; e < 50 * 25 * 9; e += 512) {
    int ci = e / 225;
    int rem = e - ci * 225;
    int co = rem / 9;
    int k  = rem - co * 9;
    wlds[(ci * 25 + co) * 12 + k] = w1[(cbase + co) * (CCH * 9) + ci * 9 + k];
  }
  __syncthreads();

  const float* ip = in + ((size_t)b * CCH << 16) + h0 * WW + w;
  const float* bb = b1 + cbase;

#define DECL(i) float A##i = bb[(i)]; float B##i = A##i;
  REPEAT25(DECL)
#undef DECL

  bool hm = h0 > 0;
  bool hp = h0 < HH - 2;
  bool wm = w > 0, wp = w < WW - 1;

  for (int ci = 0; ci < CCH; ++ci) {
    const float* p = ip + ((size_t)ci << 16);
    // 4 rows x 3 cols shared between the two output pixels
    float a0 = (hm && wm) ? p[-257] : 0.f;
    float a1 = hm         ? p[-256] : 0.f;
    float a2 = (hm && wp) ? p[-255] : 0.f;
    float r0 = wm         ? p[-1]   : 0.f;
    float r1 =              p[0];
    float r2 = wp         ? p[1]    : 0.f;
    float c0 = wm         ? p[255]  : 0.f;
    float c1 =              p[256];
    float c2 = wp         ? p[257]  : 0.f;
    float d0 = (hp && wm) ? p[511]  : 0.f;
    float d1 = hp         ? p[512]  : 0.f;
    float d2 = (hp && wp) ? p[513]  : 0.f;
    const float* wl = &wlds[ci * 25 * 12];
#define STEP(i) { \
    const float4 wA = *(const float4*)&wl[(i) * 12]; \
    const float4 wB = *(const float4*)&wl[(i) * 12 + 4]; \
    const float  w8 = wl[(i) * 12 + 8]; \
    A##i = fmaf(wA.x, a0, A##i); A##i = fmaf(wA.y, a1, A##i); A##i = fmaf(wA.z, a2, A##i); \
    A##i = fmaf(wA.w, r0, A##i); A##i = fmaf(wB.x, r1, A##i); A##i = fmaf(wB.y, r2, A##i); \
    A##i = fmaf(wB.z, c0, A##i); A##i = fmaf(wB.w, c1, A##i); A##i = fmaf(w8,  c2, A##i); \
    B##i = fmaf(wA.x, r0, B##i); B##i = fmaf(wA.y, r1, B##i); B##i = fmaf(wA.z, r2, B##i); \
    B##i = fmaf(wA.w, c0, B##i); B##i = fmaf(wB.x, c1, B##i); B##i = fmaf(wB.y, c2, B##i); \
    B##i = fmaf(wB.z, d0, B##i); B##i = fmaf(wB.w, d1, B##i); B##i = fmaf(w8,  d2, B##i); }
    REPEAT25(STEP)
#undef STEP
  }

  float* op = x1 + (((size_t)b * CCH + cbase) << 16) + h0 * WW + w;
#define STORE(i) { float* o = op + ((size_t)(i) << 16); \
    o[0]  = fmaxf(A##i, 0.f); o[WW] = fmaxf(B##i, 0.f); }
  REPEAT25(STORE)
#undef STORE
}

// ---------------- Kernel 2: conv3x3 (50->2) + softmax[:,1] ----------------
__global__ __launch_bounds__(256) void conv2_softmax_k(
    const float* __restrict__ x1, const float* __restrict__ w2,
    const float* __restrict__ b2, float* __restrict__ sm) {
  int idx = blockIdx.x * 256 + threadIdx.x;
  int b = idx >> 16, hw = idx & 65535;
  int h = hw >> 8, w = hw & 255;
  const float* ip = x1 + (size_t)b * CCH * 65536 + hw;

  float a0 = b2[0], a1 = b2[1];
  bool hm = h > 0, hp = h < HH - 1, wm = w > 0, wp = w < WW - 1;

  for (int ci = 0; ci < CCH; ++ci) {
    const float* p = ip + (size_t)ci * 65536;
    float v0 = (hm && wm) ? p[-257] : 0.f;
    float v1 = hm         ? p[-256] : 0.f;
    float v2 = (hm && wp) ? p[-255] : 0.f;
    float v3 = wm         ? p[-1]   : 0.f;
    float v4 =              p[0];
    float v5 = wp         ? p[1]    : 0.f;
    float v6 = (hp && wm) ? p[255]  : 0.f;
    float v7 = hp         ? p[256]  : 0.f;
    float v8 = (hp && wp) ? p[257]  : 0.f;
    const float* q0 = w2 + ci * 9;
    const float* q1 = w2 + CCH * 9 + ci * 9;
    a0 = fmaf(q0[0], v0, a0); a0 = fmaf(q0[1], v1, a0); a0 = fmaf(q0[2], v2, a0);
    a0 = fmaf(q0[3], v3, a0); a0 = fmaf(q0[4], v4, a0); a0 = fmaf(q0[5], v5, a0);
    a0 = fmaf(q0[6], v6, a0); a0 = fmaf(q0[7], v7, a0); a0 = fmaf(q0[8], v8, a0);
    a1 = fmaf(q1[0], v0, a1); a1 = fmaf(q1[1], v1, a1); a1 = fmaf(q1[2], v2, a1);
    a1 = fmaf(q1[3], v3, a1); a1 = fmaf(q1[4], v4, a1); a1 = fmaf(q1[5], v5, a1);
    a1 = fmaf(q1[6], v6, a1); a1 = fmaf(q1[7], v7, a1); a1 = fmaf(q1[8], v8, a1);
  }
  // softmax over {a0,a1}, channel 1 = sigmoid(a1 - a0)
  sm[(size_t)b * 65536 + hw] = 1.f / (1.f + expf(a0 - a1));
}

// ---------------- Kernel 3: 4x4 avg pool + LeakyReLU(0.1) ----------------
__global__ __launch_bounds__(256) void pool_leaky_k(
    const float* __restrict__ sm, float* __restrict__ pool) {
  int idx = blockIdx.x * 256 + threadIdx.x;      // b*4096 + hs*64 + ws
  int b = idx >> 12, hw = idx & 4095;
  int hs = hw >> 6, ws = hw & 63;
  const float* p = sm + (size_t)b * 65536 + hs * 4 * WW + ws * 4;
  float s = 0.f;
#pragma unroll
  for (int r = 0; r < 4; ++r)
#pragma unroll
    for (int c = 0; c < 4; ++c) s += p[r * WW + c];
  s *= (1.f / 16.f);
  pool[idx] = (s >= 0.f) ? s : 0.1f * s;
}

// ---------------- Kernel 4: 25-tap learned mixing -> final_mask ----------------
__global__ __launch_bounds__(256) void mix_mask_k(
    const float* __restrict__ pool, const float* __restrict__ wk,
    const float* __restrict__ bk, float* __restrict__ mask_out) {
  int idx = blockIdx.x * 256 + threadIdx.x;      // b*4096 + hs*64 + ws
  int b = idx >> 12, hw = idx & 4095;
  int hs = hw >> 6, ws = hw & 63;
  float c = pool[idx];
  float s = 0.f;
#pragma unroll
  for (int i = 0; i < 5; ++i) {
#pragma unroll
    for (int j = 0; j < 5; ++j) {
      int y = hs + i - 2, x = ws + j - 2;
      float win = (y >= 0 && y < HSZ && x >= 0 && x < WSZ)
                      ? pool[(size_t)b * 4096 + y * WSZ + x] : 0.f;
      int k = i * 5 + j;
      s += (wk[k] * c + bk[k]) * win;
    }
  }
  mask_out[idx] = s;
}

// ---------------- Kernel 5: per-batch top-240 + ascending index sort ----------------
__global__ __launch_bounds__(256) void topk_sort_k(
    const float* __restrict__ mask, float* __restrict__ ob, float* __restrict__ oh,
    float* __restrict__ ow, int* __restrict__ idx_ws) {
  __shared__ unsigned long long keys[4096];
  __shared__ int sidx[256];
  int b = blockIdx.x, t = threadIdx.x;

  for (int i = t; i < 4096; i += 256) {
    float v = mask[(size_t)b * 4096 + i];
    unsigned u = __float_as_uint(v);
    u = (u & 0x80000000u) ? ~u : (u | 0x80000000u);   // order-preserving map
    u = ~u;                                            // ascending sort -> value desc
    keys[i] = ((unsigned long long)u << 12) | (unsigned)i;  // tie: lower idx first
  }
  __syncthreads();

  // bitonic sort 4096, ascending
  for (int k = 2; k <= 4096; k <<= 1) {
    for (int j = k >> 1; j > 0; j >>= 1) {
      for (int m = t; m < 2048; m += 256) {
        int i = ((m & ~(j - 1)) << 1) | (m & (j - 1));
        int l = i | j;
        bool up = ((i & k) == 0);
        unsigned long long a = keys[i], c = keys[l];
        if ((a > c) == up) { keys[i] = c; keys[l] = a; }
      }
      __syncthreads();
    }
  }

  // first 240 entries are top-k (value desc). Extract indices, sort ascending.
  sidx[t] = (t < NTOP) ? (int)(keys[t] & 0xFFFu) : 0x7FFFFFFF;
  __syncthreads();
  for (int k = 2; k <= 256; k <<= 1) {
    for (int j = k >> 1; j > 0; j >>= 1) {
      if (t < 128) {
        int i = ((t & ~(j - 1)) << 1) | (t & (j - 1));
        int l = i | j;
        bool up = ((i & k) == 0);
        int a = sidx[i], c = sidx[l];
        if ((a > c) == up) { sidx[i] = c; sidx[l] = a; }
      }
      __syncthreads();
    }
  }

  if (t < NTOP) {
    int id = sidx[t];
    int o = b * NTOP + t;
    ob[o] = (float)b;
    oh[o] = (float)(id >> 6);
    ow[o] = (float)(id & 63);
    idx_ws[o] = id;
  }
}

// ---------------- Kernel 6: gather 6x6 patches (pad=1, stride=4) ----------------
__global__ __launch_bounds__(256) void gather_patch_k(
    const float* __restrict__ in, const int* __restrict__ idx_ws,
    float* __restrict__ patches) {
  int p = blockIdx.x;                 // 0 .. B*240-1
  int b = p / NTOP;
  int id = idx_ws[p];
  int h = id >> 6, w = id & 63;
  int y0 = h * 4 - 1, x0 = w * 4 - 1;
  const float* base = in + (size_t)b * CCH * 65536;
  float* op = patches + (size_t)p * (CCH * 36);
  for (int e = threadIdx.x; e < CCH * 36; e += 256) {
    int c = e / 36;
    int r = (e - c * 36) / 6;
    int col = e - c * 36 - r * 6;
    int y = y0 + r, x = x0 + col;
    float v = 0.f;
    if (y >= 0 && y < HH && x >= 0 && x < WW)
      v = base[(size_t)c * 65536 + y * WW + x];
    op[e] = v;
  }
}

extern "C" void kernel_launch(void* const* d_in, const int* in_sizes, int n_in,
                              void* d_out, int out_size, void* d_ws, size_t ws_size,
                              hipStream_t stream) {
  const float* out_lr = (const float*)d_in[0];
  const float* W1 = (const float*)d_in[1];
  const float* b1 = (const float*)d_in[2];
  const float* W2 = (const float*)d_in[3];
  const float* b2 = (const float*)d_in[4];
  const float* Wk = (const float*)d_in[5];
  const float* bk = (const float*)d_in[6];

  // workspace layout
  float* x1   = (float*)d_ws;                 // 16*50*256*256 = 52,428,800
  float* sm   = x1 + (size_t)52428800;        // 16*256*256    =  1,048,576
  float* pool = sm + (size_t)1048576;         // 16*64*64      =     65,536
  int*  idxb  = (int*)(pool + 65536);         // 16*240        =      3,840

  // output layout (float32, concatenated in reference return order)
  float* out    = (float*)d_out;
  float* o_patch = out;                        // 3840*50*36 = 6,912,000
  float* o_b    = out + (size_t)6912000;       // 3840
  float* o_h    = o_b + 3840;                  // 3840
  float* o_w    = o_h + 3840;                  // 3840
  float* o_mask = o_w + 3840;                  // 16*4096 = 65,536

  conv1_relu_k<<<BATCH * 64 * 2, 512, 0, stream>>>(out_lr, W1, b1, x1);
  conv2_softmax_k<<<4096, 256, 0, stream>>>(x1, W2, b2, sm);
  pool_leaky_k<<<256, 256, 0, stream>>>(sm, pool);
  mix_mask_k<<<256, 256, 0, stream>>>(pool, Wk, bk, o_mask);
  topk_sort_k<<<BATCH, 256, 0, stream>>>(o_mask, o_b, o_h, o_w, idxb);
  gather_patch_k<<<BATCH * NTOP, 256, 0, stream>>>(out_lr, idxb, o_patch);
}